// Round 9
// baseline (212.646 us; speedup 1.0000x reference)
//
#include <hip/hip_runtime.h>

// Interface (pinned): inputs fp32, mask int32, OUTPUT fp32.
// R17 (resubmit; previous round was an infra failure -- container acquire
// failed twice, kernel never ran) = R16 + transpose_v DELETED: gemm_proj
// z==2 writes vtg directly via an LDS-routed transpose in its epilogue.
//   R16 post-mortem: gload_lds on the GEMMs was null -> GEMMs are not
//   staging-throughput-bound; non-attn (161.8us, 6 dispatches, each <44.6)
//   is stable across all staging treatments. Only guaranteed-sign lever:
//   fewer dispatches / fewer intermediate passes.
//   R13's version of this fusion failed on 8B-segment scattered global
//   stores; this one keeps BOTH global sides coalesced:
//     acc -> (f2bf, scalar) -> tr LDS [128key][130pad] -> barrier ->
//     8-key-octet reads -> bf16x8 stores, 256B-contiguous per 16 lanes.
//   Values bit-identical (same f2bf(acc+bias) bits, rerouted through LDS).
//   LDS: tr reuses the K-loop staging arrays after the final barrier
//   (one 33KB block, 4 blocks/CU unchanged). vb buffer deleted (-16MB HBM).
// attn = R13 exact (best verified 44.6-44.9us). mlp/ln/transpose_w = R16.

typedef float f32x4 __attribute__((ext_vector_type(4)));
typedef short bf16x8 __attribute__((ext_vector_type(8)));
typedef unsigned short u16;

#define MFMA16 __builtin_amdgcn_mfma_f32_16x16x32_bf16

__device__ __forceinline__ float bf2f(u16 u){
    unsigned x = ((unsigned)u) << 16;
    return __builtin_bit_cast(float, x);
}
__device__ __forceinline__ u16 f2bf(float f){  // round-to-nearest-even
    unsigned u = __builtin_bit_cast(unsigned, f);
    u = u + 0x7fffu + ((u >> 16) & 1u);
    return (u16)(u >> 16);
}

// Direct global->LDS copy, 16B per lane. LDS dest is WAVE-UNIFORM base +
// lane*16 (m104): pass the wave's base; per-lane g covers the swizzle.
__device__ __forceinline__ void gload_lds16(const u16* g, u16* l){
    __builtin_amdgcn_global_load_lds(
        (const __attribute__((address_space(1))) void*)g,
        (__attribute__((address_space(3))) void*)l, 16, 0, 0);
}

// ---------------------------------------------------------------------------
// Transpose + fp32->bf16 the 4 weight matrices (512x512).
// ---------------------------------------------------------------------------
__global__ __launch_bounds__(256) void transpose_w(
    const float* __restrict__ Wq, const float* __restrict__ Wk,
    const float* __restrict__ Wv, const float* __restrict__ Wo,
    u16* __restrict__ wt)
{
    const int z = blockIdx.z;
    const float* W = (z == 0) ? Wq : (z == 1) ? Wk : (z == 2) ? Wv : Wo;
    u16* out = wt + (size_t)z * 512 * 512;

    __shared__ u16 tile[32][33];
    const int k0 = blockIdx.y * 32, n0 = blockIdx.x * 32;
    const int c = threadIdx.x & 31, r = threadIdx.x >> 5;
#pragma unroll
    for (int i = 0; i < 4; i++) {
        int rr = r + i * 8;
        tile[rr][c] = f2bf(W[(size_t)(k0 + rr) * 512 + n0 + c]);
    }
    __syncthreads();
#pragma unroll
    for (int i = 0; i < 4; i++) {
        int rr = r + i * 8;
        out[(size_t)(n0 + rr) * 512 + k0 + c] = tile[c][rr];
    }
}

// ---------------------------------------------------------------------------
// Projection GEMM: C = X(fp32) @ W(bf16^T) + bias (R9-verified math).
// z==0 -> qb, z==1 -> kb (row-major [row][col] bf16 stores).
// z==2 -> vtg DIRECTLY: acc -> tr LDS [128key][130] -> coalesced bf16x8
//         stores to vtg[(b*8+h)*64+d][1024 keys]. transpose_v deleted.
// B-tile staged via global_load_lds (linear LDS + XOR chunk swizzle);
// A-tile via the verified fp32->bf16 VGPR path (padded lds_a).
// ---------------------------------------------------------------------------
__global__ __launch_bounds__(256) void gemm_proj(
    const float* __restrict__ Q, const float* __restrict__ K,
    const u16* __restrict__ wt,
    const float* __restrict__ bq, const float* __restrict__ bk, const float* __restrict__ bv,
    u16* __restrict__ qb, u16* __restrict__ kb, u16* __restrict__ vtg)
{
    // One LDS block, region-aliased:
    //   K-loop:  lds_a = raw[0 .. 5120)   (128*40, padded ds_write staging)
    //            lds_b = raw[5120 .. 9216) (128*32, linear gload_lds dest)
    //   epilogue (z==2 only, after final barrier): tr = raw[0 .. 16640)
    __shared__ __align__(16) u16 lds_raw[128 * 130];
    u16* lds_a = lds_raw;
    u16* lds_b = lds_raw + 128 * 40;

    const int z = blockIdx.z;
    const float* X = (z == 0) ? Q : K;
    const u16* Wt = wt + (size_t)z * 512 * 512;
    const float* bias = (z == 0) ? bq : (z == 1) ? bk : bv;

    const int bm = blockIdx.y, bn = blockIdx.x;
    const int t = threadIdx.x;
    const int wave = t >> 6, lane = t & 63, quad = lane >> 4, lm = lane & 15;
    const int wm = wave >> 1, wn = wave & 1;

    // B staging geometry (R16-verified): lane l -> row j*64+wave*16+(l>>2),
    // phys chunk l&3; global source pre-swizzled with chunk^=(row&3).
    const u16* bsrc[2];
    u16* bdst[2];
#pragma unroll
    for (int j = 0; j < 2; j++) {
        const int r = j * 64 + wave * 16 + (lane >> 2);
        const int cg = ((lane & 3) ^ (r & 3)) * 8;
        bsrc[j] = &Wt[(size_t)(bn * 128 + r) * 512 + cg];
        bdst[j] = &lds_b[(j * 2048) + wave * 512];   // u16 units; wave-uniform
    }

    f32x4 acc[4][4];
    const f32x4 zz = {0.f, 0.f, 0.f, 0.f};
#pragma unroll
    for (int i = 0; i < 4; i++)
#pragma unroll
        for (int j = 0; j < 4; j++) acc[i][j] = zz;

    for (int k0 = 0; k0 < 512; k0 += 32) {
        gload_lds16(bsrc[0] + k0, bdst[0]);
        gload_lds16(bsrc[1] + k0, bdst[1]);
#pragma unroll
        for (int i = 0; i < 2; i++) {
            int idx = t + i * 256;
            int r = idx >> 2, c = (idx & 3) * 8;
            const float* xp = &X[(size_t)(bm * 128 + r) * 512 + k0 + c];
            f32x4 a0 = *(const f32x4*)xp;
            f32x4 a1 = *(const f32x4*)(xp + 4);
            bf16x8 xv;
#pragma unroll
            for (int j = 0; j < 4; j++) { xv[j] = (short)f2bf(a0[j]); xv[4 + j] = (short)f2bf(a1[j]); }
            *(bf16x8*)&lds_a[r * 40 + c] = xv;
        }
        __syncthreads();
        bf16x8 af[4], bfr[4];
#pragma unroll
        for (int mi = 0; mi < 4; mi++)
            af[mi] = *(const bf16x8*)&lds_a[(wm * 64 + mi * 16 + lm) * 40 + quad * 8];
#pragma unroll
        for (int ni = 0; ni < 4; ni++)
            bfr[ni] = *(const bf16x8*)&lds_b[(wn * 64 + ni * 16 + lm) * 32
                                            + ((quad ^ (lm & 3)) * 8)];
#pragma unroll
        for (int mi = 0; mi < 4; mi++)
#pragma unroll
            for (int ni = 0; ni < 4; ni++)
                acc[mi][ni] = MFMA16(af[mi], bfr[ni], acc[mi][ni], 0, 0, 0);
        __syncthreads();   // also protects lds_raw before epilogue reuse
    }

    if (z == 2) {
        // ---- transposed V epilogue: acc -> tr[key][130] -> vtg ----
        // tr pad 130 u16 (65 dw, odd): write/read conflicts ~4-way, once.
#pragma unroll
        for (int mi = 0; mi < 4; mi++) {
            const int keyl = wm * 64 + mi * 16 + quad * 4;
#pragma unroll
            for (int ni = 0; ni < 4; ni++) {
                const int dl = wn * 64 + ni * 16 + lm;
                const float bv_ = bias[bn * 128 + dl];
#pragma unroll
                for (int r = 0; r < 4; r++)
                    lds_raw[(keyl + r) * 130 + dl] = f2bf(acc[mi][ni][r] + bv_);
            }
        }
        __syncthreads();
        // store: task = (d 0..127) x (key-octet 0..15); lane t -> ko = t&15,
        // d = i*16 + (t>>4). 16 lanes = 256B contiguous keys for one d.
        const int bb = bm >> 3;                    // batch index
        const int keycol = (bm & 7) * 128;         // key base within 1024
#pragma unroll
        for (int i = 0; i < 8; i++) {
            const int dl = i * 16 + (t >> 4);
            const int ko = t & 15;
            const int dg = bn * 128 + dl;          // global V feature dim
            const int hh = dg >> 6, dd = dg & 63;
            bf16x8 v;
#pragma unroll
            for (int j = 0; j < 8; j++)
                v[j] = (short)lds_raw[(ko * 8 + j) * 130 + dl];
            *(bf16x8*)&vtg[((size_t)((bb * 8 + hh) * 64 + dd)) * 1024
                           + keycol + ko * 8] = v;
        }
    } else {
        u16* outb = (z == 0) ? qb : kb;
#pragma unroll
        for (int mi = 0; mi < 4; mi++) {
#pragma unroll
            for (int ni = 0; ni < 4; ni++) {
                const int col = bn * 128 + wn * 64 + ni * 16 + lm;
                const float bv_ = bias[col];
#pragma unroll
                for (int r = 0; r < 4; r++) {
                    const int row = bm * 128 + wm * 64 + mi * 16 + quad * 4 + r;
                    outb[(size_t)row * 512 + col] = f2bf(acc[mi][ni][r] + bv_);
                }
            }
        }
    }
}

// ---------------------------------------------------------------------------
// MLP GEMM: Uf = resid(fp32) + relu(X(bf16) @ Wo^T + bo) -> fp32.
// BOTH tiles staged via global_load_lds (linear LDS + XOR chunk swizzle).
// ---------------------------------------------------------------------------
__global__ __launch_bounds__(256) void gemm_mlp(
    const u16* __restrict__ X, const u16* __restrict__ wt,
    const float* __restrict__ bo, const float* __restrict__ resid,
    float* __restrict__ outf)
{
    __shared__ __align__(16) u16 lds_a[128 * 32];
    __shared__ __align__(16) u16 lds_b[128 * 32];

    const u16* Wt = wt + (size_t)3 * 512 * 512;
    const int bm = blockIdx.y, bn = blockIdx.x;
    const int t = threadIdx.x;
    const int wave = t >> 6, lane = t & 63, quad = lane >> 4, lm = lane & 15;
    const int wm = wave >> 1, wn = wave & 1;

    const u16* asrc[2];
    const u16* bsrc[2];
    u16* adst[2];
    u16* bdst[2];
#pragma unroll
    for (int j = 0; j < 2; j++) {
        const int r = j * 64 + wave * 16 + (lane >> 2);
        const int cg = ((lane & 3) ^ (r & 3)) * 8;
        asrc[j] = &X [(size_t)(bm * 128 + r) * 512 + cg];
        bsrc[j] = &Wt[(size_t)(bn * 128 + r) * 512 + cg];
        adst[j] = &lds_a[(j * 2048) + wave * 512];
        bdst[j] = &lds_b[(j * 2048) + wave * 512];
    }

    f32x4 acc[4][4];
    const f32x4 zz = {0.f, 0.f, 0.f, 0.f};
#pragma unroll
    for (int i = 0; i < 4; i++)
#pragma unroll
        for (int j = 0; j < 4; j++) acc[i][j] = zz;

    for (int k0 = 0; k0 < 512; k0 += 32) {
        gload_lds16(asrc[0] + k0, adst[0]);
        gload_lds16(asrc[1] + k0, adst[1]);
        gload_lds16(bsrc[0] + k0, bdst[0]);
        gload_lds16(bsrc[1] + k0, bdst[1]);
        __syncthreads();
        bf16x8 af[4], bfr[4];
        const int cxor = (quad ^ (lm & 3)) * 8;
#pragma unroll
        for (int mi = 0; mi < 4; mi++)
            af[mi] = *(const bf16x8*)&lds_a[(wm * 64 + mi * 16 + lm) * 32 + cxor];
#pragma unroll
        for (int ni = 0; ni < 4; ni++)
            bfr[ni] = *(const bf16x8*)&lds_b[(wn * 64 + ni * 16 + lm) * 32 + cxor];
#pragma unroll
        for (int mi = 0; mi < 4; mi++)
#pragma unroll
            for (int ni = 0; ni < 4; ni++)
                acc[mi][ni] = MFMA16(af[mi], bfr[ni], acc[mi][ni], 0, 0, 0);
        __syncthreads();
    }

#pragma unroll
    for (int mi = 0; mi < 4; mi++) {
#pragma unroll
        for (int ni = 0; ni < 4; ni++) {
            const int col = bn * 128 + wn * 64 + ni * 16 + lm;
            const float bv_ = bo[col];
#pragma unroll
            for (int r = 0; r < 4; r++) {
                const int row = bm * 128 + wm * 64 + mi * 16 + quad * 4 + r;
                const size_t off = (size_t)row * 512 + col;
                outf[off] = resid[off] + fmaxf(acc[mi][ni][r] + bv_, 0.f);
            }
        }
    }
}

// ---------------------------------------------------------------------------
// Attention (R13-verified, best 44.6us): block = (b, h, 64 q-rows), 4 waves
// x 16 q, grid 1024, 16 waves/CU. K AND V staged in LDS via reg double-
// buffer (coalesced VMEM); 2 barriers/tile. Mask bias via 4 coalesced VMEM
// loads/tile. P: R8-verified per-wave RNE-bf16-through-LDS. XCD swizzle.
// ---------------------------------------------------------------------------
__global__ __launch_bounds__(256, 4) void attn_kernel(
    const u16* __restrict__ qb, const u16* __restrict__ kb, const u16* __restrict__ vtg,
    const int* __restrict__ mask, float* __restrict__ O)
{
    __shared__ __align__(16) u16 k_tile[64 * 88];       // [key][d]
    __shared__ __align__(16) u16 vt[64 * 88];           // [d][key]
    __shared__ __align__(16) u16 p_st[4 * 16 * 88];     // per-wave [qrow][key]

    // XCD swizzle: xcd = i&7; all 16 q-tiles of one (b,h) land on one XCD.
    const int i = blockIdx.x;
    const int s_ = i >> 3;
    const int bh = (i & 7) + 8 * (s_ >> 4);
    const int qt = s_ & 15;
    const int b = bh >> 3, h = bh & 7;

    const int t = threadIdx.x, wave = t >> 6, lane = t & 63;
    const int quad = lane >> 4, lm = lane & 15;
    const int qbase = qt * 64 + wave * 16;
    const size_t baseb = (size_t)b * 1024 * 512;
    const size_t vbase = (size_t)((b * 8 + h) * 64) * 1024;
    const int* mrow = &mask[b * 1024];

    // Q A-frags: 1 m-tile (16 q-rows) x 2 d-halves
    bf16x8 aq[2];
#pragma unroll
    for (int ks = 0; ks < 2; ks++)
        aq[ks] = *(const bf16x8*)&qb[baseb +
            (size_t)(qbase + lm) * 512 + h * 64 + ks * 32 + quad * 8];

    float lsum[4] = {0.f, 0.f, 0.f, 0.f};
    f32x4 oacc[4];
    const f32x4 zz = {0.f, 0.f, 0.f, 0.f};
#pragma unroll
    for (int c = 0; c < 4; c++) oacc[c] = zz;

    const float SC2 = 0.125f * 1.44269504088896341f; // (1/sqrt(64)) * log2(e)
    const int srow = t >> 2, scol = (t & 3) * 16;    // staging: 64 rows x 64
    u16* pw = &p_st[wave * 16 * 88];

    const u16* kgp = &kb[baseb + (size_t)srow * 512 + h * 64 + scol];
    const u16* vgp = &vtg[vbase + (size_t)srow * 1024 + scol];

    bf16x8 kA0, kA1, vA0, vA1, kB0, kB1, vB0, vB1;

    auto load_t = [&](int kt, bf16x8& k0, bf16x8& k1, bf16x8& v0, bf16x8& v1) {
        const u16* kp = kgp + (size_t)kt * 64 * 512;
        k0 = *(const bf16x8*)kp;
        k1 = *(const bf16x8*)(kp + 8);
        const u16* vp = vgp + kt * 64;
        v0 = *(const bf16x8*)vp;
        v1 = *(const bf16x8*)(vp + 8);
    };
    auto store_t = [&](bf16x8 k0, bf16x8 k1, bf16x8 v0, bf16x8 v1) {
        *(bf16x8*)&k_tile[srow * 88 + scol]     = k0;
        *(bf16x8*)&k_tile[srow * 88 + scol + 8] = k1;
        *(bf16x8*)&vt[srow * 88 + scol]     = v0;
        *(bf16x8*)&vt[srow * 88 + scol + 8] = v1;
    };

    auto compute_t = [&](int kt) {
        const int keyg = kt * 64;
        // mask bias per n-tile via coalesced VMEM (0 / -30000, same values)
        float bias_n[4];
#pragma unroll
        for (int n = 0; n < 4; n++)
            bias_n[n] = mrow[keyg + n * 16 + lm] ? 0.0f : -30000.0f;

        bf16x8 bk[4][2];
#pragma unroll
        for (int n = 0; n < 4; n++)
#pragma unroll
            for (int ks = 0; ks < 2; ks++)
                bk[n][ks] = *(const bf16x8*)&k_tile[(n * 16 + lm) * 88 + ks * 32 + quad * 8];

#pragma unroll
        for (int n = 0; n < 4; n++) {
            f32x4 S = zz;
            __builtin_amdgcn_s_setprio(1);
            S = MFMA16(aq[0], bk[n][0], S, 0, 0, 0);
            S = MFMA16(aq[1], bk[n][1], S, 0, 0, 0);
            __builtin_amdgcn_s_setprio(0);
#pragma unroll
            for (int r = 0; r < 4; r++) {
                float p = __builtin_amdgcn_exp2f(__builtin_fmaf(S[r], SC2, bias_n[n]));
                lsum[r] += p;
                pw[(quad * 4 + r) * 88 + n * 16 + lm] = f2bf(p);
            }
        }
        // no barrier: pw is per-wave; in-wave LDS RAW is program-ordered.

#pragma unroll
        for (int ks = 0; ks < 2; ks++) {
            bf16x8 ap = *(const bf16x8*)&pw[lm * 88 + ks * 32 + quad * 8];
            __builtin_amdgcn_s_setprio(1);
#pragma unroll
            for (int c = 0; c < 4; c++) {
                bf16x8 bv_ = *(const bf16x8*)&vt[(c * 16 + lm) * 88 + ks * 32 + quad * 8];
                oacc[c] = MFMA16(ap, bv_, oacc[c], 0, 0, 0);
            }
            __builtin_amdgcn_s_setprio(0);
        }
    };

    // prologue: tile 0 into regs
    load_t(0, kA0, kA1, vA0, vA1);

    for (int kt = 0; kt < 16; kt += 2) {
        store_t(kA0, kA1, vA0, vA1);          // vmcnt wait for tile kt here
        load_t(kt + 1, kB0, kB1, vB0, vB1);   // issue tile kt+1 (hidden)
        __syncthreads();
        compute_t(kt);
        __syncthreads();
        store_t(kB0, kB1, vB0, vB1);
        load_t((kt + 2) & 15, kA0, kA1, vA0, vA1); // &15: last iter dead-loads tile 0
        __syncthreads();
        compute_t(kt + 1);
        __syncthreads();
    }

    // reduce lsum across the 16 key-columns (lanes lm within each quad)
#pragma unroll
    for (int r = 0; r < 4; r++) {
        float s = lsum[r];
        s += __shfl_xor(s, 1); s += __shfl_xor(s, 2);
        s += __shfl_xor(s, 4); s += __shfl_xor(s, 8);
        lsum[r] = s;
    }

    // epilogue: O = q + P.V / l  (fp32, coalesced over lm)
#pragma unroll
    for (int c = 0; c < 4; c++)
#pragma unroll
        for (int r = 0; r < 4; r++) {
            const int row = qbase + quad * 4 + r;
            const int d = h * 64 + c * 16 + lm;
            const size_t off = baseb + (size_t)row * 512 + d;
            O[off] = bf2f(qb[off]) + oacc[c][r] / lsum[r];
        }
}

// ---------------------------------------------------------------------------
// Row LayerNorm over 512 (verified R5): fp32 in; optional bf16 + fp32 outs.
// ---------------------------------------------------------------------------
__global__ __launch_bounds__(256) void ln_kernel(
    const float* __restrict__ in, const float* __restrict__ g, const float* __restrict__ bsh,
    u16* __restrict__ outb, float* __restrict__ outf)
{
    const int row = blockIdx.x * 4 + (threadIdx.x >> 6);
    const int lane = threadIdx.x & 63;
    const float* x = in + (size_t)row * 512 + lane * 8;
    float v[8];
    *(f32x4*)&v[0] = *(const f32x4*)&x[0];
    *(f32x4*)&v[4] = *(const f32x4*)&x[4];
    float s = 0.f, sq = 0.f;
#pragma unroll
    for (int j = 0; j < 8; j++) { s += v[j]; sq += v[j] * v[j]; }
#pragma unroll
    for (int off = 1; off < 64; off <<= 1) {
        s += __shfl_xor(s, off);
        sq += __shfl_xor(sq, off);
    }
    const float mu = s * (1.f / 512.f);
    const float var = sq * (1.f / 512.f) - mu * mu;
    const float rs = rsqrtf(var + 1e-5f);
    float y[8];
#pragma unroll
    for (int j = 0; j < 8; j++) {
        int col = lane * 8 + j;
        y[j] = (v[j] - mu) * rs * g[col] + bsh[col];
    }
    if (outb != nullptr) {
        bf16x8 ov;
#pragma unroll
        for (int j = 0; j < 8; j++) ov[j] = (short)f2bf(y[j]);
        *(bf16x8*)&outb[(size_t)row * 512 + lane * 8] = ov;
    }
    if (outf != nullptr) {
        float* o = outf + (size_t)row * 512 + lane * 8;
        *(f32x4*)&o[0] = *(const f32x4*)&y[0];
        *(f32x4*)&o[4] = *(const f32x4*)&y[4];
    }
}

extern "C" void kernel_launch(void* const* d_in, const int* in_sizes, int n_in,
                              void* d_out, int out_size, void* d_ws, size_t ws_size,
                              hipStream_t stream) {
    const float* Q  = (const float*)d_in[0];
    const float* K  = (const float*)d_in[1];
    const int* mask = (const int*)d_in[2];
    const float* Wq = (const float*)d_in[3];
    const float* bq = (const float*)d_in[4];
    const float* Wk = (const float*)d_in[5];
    const float* bk = (const float*)d_in[6];
    const float* Wv = (const float*)d_in[7];
    const float* bv = (const float*)d_in[8];
    const float* Wo = (const float*)d_in[9];
    const float* bo = (const float*)d_in[10];
    const float* g0 = (const float*)d_in[11];
    const float* b0 = (const float*)d_in[12];
    const float* g1 = (const float*)d_in[13];
    const float* b1 = (const float*)d_in[14];
    float* out = (float*)d_out;

    char* ws = (char*)d_ws;
    const size_t MB = 1048576;
    // Liveness (peak 42 MiB):
    //   gemm_proj: W qb(2-10) kb(10-18) vtg(18-26)
    //   attn:      R qb,kb,vtg      W Of(26-42)
    //   ln0:       R Of             W O1b(2-10) O1f(10-26)
    //   gemm_mlp:  R O1b,wt,O1f     W Uf(26-42)
    //   ln1:       R Uf             W out
    u16*   wt  = (u16*)(ws);
    u16*   qb  = (u16*)(ws + 2 * MB);
    u16*   kb  = (u16*)(ws + 10 * MB);
    u16*   vtg = (u16*)(ws + 18 * MB);
    float* Of  = (float*)(ws + 26 * MB);
    u16*   O1b = (u16*)(ws + 2 * MB);     // reuse qb
    float* O1f = (float*)(ws + 10 * MB);  // reuse kb+vtg
    float* Uf  = (float*)(ws + 26 * MB);  // reuse Of

    transpose_w<<<dim3(16, 16, 4), 256, 0, stream>>>(Wq, Wk, Wv, Wo, wt);
    gemm_proj<<<dim3(4, 64, 3), 256, 0, stream>>>(Q, K, wt, bq, bk, bv, qb, kb, vtg);
    attn_kernel<<<1024, 256, 0, stream>>>(qb, kb, vtg, mask, Of);
    ln_kernel<<<2048, 256, 0, stream>>>(Of, g0, b0, O1b, O1f);
    gemm_mlp<<<dim3(4, 64, 1), 256, 0, stream>>>(O1b, wt, bo, O1f, Uf);
    ln_kernel<<<2048, 256, 0, stream>>>(Uf, g1, b1, nullptr, out);
}

// Round 10
// 202.531 us; speedup vs baseline: 1.0499x; 1.0499x over previous
//
#include <hip/hip_runtime.h>

// Interface (pinned): inputs fp32, mask int32, OUTPUT fp32.
// R18 = R16 exact (fusion epilogue reverted: it cost +6us -- proj 48us with
// the LDS-transpose tail; vb + transpose_v restored) + XCD-aware block
// remap (T1) on BOTH GEMMs:
//   R17's profile finally exposed gemm_proj: 48us, FETCH 100MB (inputs are
//   34MB!), 2.6TB/s. Cause: flat id f=bn+4*bm -> XCD=f&7 puts the 4
//   bn-blocks sharing one A row-panel on 4 DIFFERENT XCDs (4x A fetch,
//   192MB logical) and gives each XCD a 8MB A working set (thrashes 4MB L2).
//   Remap (bijective, in-kernel, zero numerics risk): each XCD gets all
//   4 bn x 8 contiguous bm per z -> A panel fetched by exactly one XCD;
//   working set 2.5MB < 4MB L2.
// attn = R13 exact (best verified 44.6us). ln/transpose_w/WS = R16.

typedef float f32x4 __attribute__((ext_vector_type(4)));
typedef short bf16x8 __attribute__((ext_vector_type(8)));
typedef unsigned short u16;

#define MFMA16 __builtin_amdgcn_mfma_f32_16x16x32_bf16

__device__ __forceinline__ float bf2f(u16 u){
    unsigned x = ((unsigned)u) << 16;
    return __builtin_bit_cast(float, x);
}
__device__ __forceinline__ u16 f2bf(float f){  // round-to-nearest-even
    unsigned u = __builtin_bit_cast(unsigned, f);
    u = u + 0x7fffu + ((u >> 16) & 1u);
    return (u16)(u >> 16);
}

// Direct global->LDS copy, 16B per lane. LDS dest is WAVE-UNIFORM base +
// lane*16 (m104): pass the wave's base; per-lane g covers the swizzle.
__device__ __forceinline__ void gload_lds16(const u16* g, u16* l){
    __builtin_amdgcn_global_load_lds(
        (const __attribute__((address_space(1))) void*)g,
        (__attribute__((address_space(3))) void*)l, 16, 0, 0);
}

// ---------------------------------------------------------------------------
// Transpose + fp32->bf16 the 4 weight matrices (512x512).
// ---------------------------------------------------------------------------
__global__ __launch_bounds__(256) void transpose_w(
    const float* __restrict__ Wq, const float* __restrict__ Wk,
    const float* __restrict__ Wv, const float* __restrict__ Wo,
    u16* __restrict__ wt)
{
    const int z = blockIdx.z;
    const float* W = (z == 0) ? Wq : (z == 1) ? Wk : (z == 2) ? Wv : Wo;
    u16* out = wt + (size_t)z * 512 * 512;

    __shared__ u16 tile[32][33];
    const int k0 = blockIdx.y * 32, n0 = blockIdx.x * 32;
    const int c = threadIdx.x & 31, r = threadIdx.x >> 5;
#pragma unroll
    for (int i = 0; i < 4; i++) {
        int rr = r + i * 8;
        tile[rr][c] = f2bf(W[(size_t)(k0 + rr) * 512 + n0 + c]);
    }
    __syncthreads();
#pragma unroll
    for (int i = 0; i < 4; i++) {
        int rr = r + i * 8;
        out[(size_t)(n0 + rr) * 512 + k0 + c] = tile[c][rr];
    }
}

// ---------------------------------------------------------------------------
// Transpose V: vb[8192][512] (bf16) -> vtg[(b*8+h)*64 + d][1024 keys] (bf16).
// ---------------------------------------------------------------------------
__global__ __launch_bounds__(256) void transpose_v(
    const u16* __restrict__ vb, u16* __restrict__ vtg)
{
    __shared__ u16 tile[32][33];
    const int bh = blockIdx.z;              // 0..63
    const int b = bh >> 3, h = bh & 7;
    const int k0 = blockIdx.x * 32, d0 = blockIdx.y * 32;
    const int c = threadIdx.x & 31, r = threadIdx.x >> 5;
#pragma unroll
    for (int i = 0; i < 4; i++) {
        int rr = r + i * 8;
        tile[rr][c] = vb[(size_t)(b * 1024 + k0 + rr) * 512 + h * 64 + d0 + c];
    }
    __syncthreads();
#pragma unroll
    for (int i = 0; i < 4; i++) {
        int rr = r + i * 8;
        vtg[(size_t)(bh * 64 + d0 + rr) * 1024 + k0 + c] = tile[c][rr];
    }
}

// ---------------------------------------------------------------------------
// Projection GEMM: C = X(fp32) @ W(bf16^T) + bias -> bf16 (R9-verified math).
// XCD remap: f = bx+4*by+256*bz; xcd=f&7; s=f>>3; z=s>>5;
//            bm = xcd*8 + ((s&31)>>2); bn = s&3.   (bijective)
// Per XCD per z: all 4 bn x 8 bm -> A panel fetched once, WS 2.5MB < L2.
// B-tile staged via global_load_lds (linear LDS + XOR chunk swizzle);
// A-tile via the verified fp32->bf16 VGPR path (padded lds_a).
// ---------------------------------------------------------------------------
__global__ __launch_bounds__(256) void gemm_proj(
    const float* __restrict__ Q, const float* __restrict__ K,
    const u16* __restrict__ wt,
    const float* __restrict__ bq, const float* __restrict__ bk, const float* __restrict__ bv,
    u16* __restrict__ qb, u16* __restrict__ kb, u16* __restrict__ vb)
{
    __shared__ __align__(16) u16 lds_a[128 * 40];   // padded (ds_write staged)
    __shared__ __align__(16) u16 lds_b[128 * 32];   // linear (gload_lds dest)

    // XCD-aware remap (see header).
    const int f = blockIdx.x + (blockIdx.y << 2) + (blockIdx.z << 8);
    const int xcd = f & 7, s = f >> 3;
    const int z = s >> 5;
    const int r_ = s & 31;
    const int bm = xcd * 8 + (r_ >> 2);
    const int bn = r_ & 3;

    const float* X = (z == 0) ? Q : K;
    const u16* Wt = wt + (size_t)z * 512 * 512;
    const float* bias = (z == 0) ? bq : (z == 1) ? bk : bv;
    u16* outb = (z == 0) ? qb : (z == 1) ? kb : vb;

    const int t = threadIdx.x;
    const int wave = t >> 6, lane = t & 63, quad = lane >> 4, lm = lane & 15;
    const int wm = wave >> 1, wn = wave & 1;

    // B staging geometry (R16-verified): lane l -> row j*64+wave*16+(l>>2),
    // phys chunk l&3; global source pre-swizzled with chunk^=(row&3).
    const u16* bsrc[2];
    u16* bdst[2];
#pragma unroll
    for (int j = 0; j < 2; j++) {
        const int r = j * 64 + wave * 16 + (lane >> 2);
        const int cg = ((lane & 3) ^ (r & 3)) * 8;
        bsrc[j] = &Wt[(size_t)(bn * 128 + r) * 512 + cg];
        bdst[j] = &lds_b[(j * 2048) + wave * 512];   // u16 units; wave-uniform
    }

    f32x4 acc[4][4];
    const f32x4 zz = {0.f, 0.f, 0.f, 0.f};
#pragma unroll
    for (int i = 0; i < 4; i++)
#pragma unroll
        for (int j = 0; j < 4; j++) acc[i][j] = zz;

    for (int k0 = 0; k0 < 512; k0 += 32) {
        gload_lds16(bsrc[0] + k0, bdst[0]);
        gload_lds16(bsrc[1] + k0, bdst[1]);
#pragma unroll
        for (int i = 0; i < 2; i++) {
            int idx = t + i * 256;
            int r = idx >> 2, c = (idx & 3) * 8;
            const float* xp = &X[(size_t)(bm * 128 + r) * 512 + k0 + c];
            f32x4 a0 = *(const f32x4*)xp;
            f32x4 a1 = *(const f32x4*)(xp + 4);
            bf16x8 xv;
#pragma unroll
            for (int j = 0; j < 4; j++) { xv[j] = (short)f2bf(a0[j]); xv[4 + j] = (short)f2bf(a1[j]); }
            *(bf16x8*)&lds_a[r * 40 + c] = xv;
        }
        __syncthreads();
        bf16x8 af[4], bfr[4];
#pragma unroll
        for (int mi = 0; mi < 4; mi++)
            af[mi] = *(const bf16x8*)&lds_a[(wm * 64 + mi * 16 + lm) * 40 + quad * 8];
#pragma unroll
        for (int ni = 0; ni < 4; ni++)
            bfr[ni] = *(const bf16x8*)&lds_b[(wn * 64 + ni * 16 + lm) * 32
                                            + ((quad ^ (lm & 3)) * 8)];
#pragma unroll
        for (int mi = 0; mi < 4; mi++)
#pragma unroll
            for (int ni = 0; ni < 4; ni++)
                acc[mi][ni] = MFMA16(af[mi], bfr[ni], acc[mi][ni], 0, 0, 0);
        __syncthreads();
    }

#pragma unroll
    for (int mi = 0; mi < 4; mi++) {
#pragma unroll
        for (int ni = 0; ni < 4; ni++) {
            const int col = bn * 128 + wn * 64 + ni * 16 + lm;
            const float bv_ = bias[col];
#pragma unroll
            for (int r = 0; r < 4; r++) {
                const int row = bm * 128 + wm * 64 + mi * 16 + quad * 4 + r;
                outb[(size_t)row * 512 + col] = f2bf(acc[mi][ni][r] + bv_);
            }
        }
    }
}

// ---------------------------------------------------------------------------
// MLP GEMM: Uf = resid(fp32) + relu(X(bf16) @ Wo^T + bo) -> fp32.
// XCD remap: f = bx+4*by; xcd=f&7; s=f>>3; bm = xcd*8+(s>>2); bn = s&3.
// BOTH tiles staged via global_load_lds (linear LDS + XOR chunk swizzle).
// ---------------------------------------------------------------------------
__global__ __launch_bounds__(256) void gemm_mlp(
    const u16* __restrict__ X, const u16* __restrict__ wt,
    const float* __restrict__ bo, const float* __restrict__ resid,
    float* __restrict__ outf)
{
    __shared__ __align__(16) u16 lds_a[128 * 32];
    __shared__ __align__(16) u16 lds_b[128 * 32];

    const u16* Wt = wt + (size_t)3 * 512 * 512;

    const int f = blockIdx.x + (blockIdx.y << 2);
    const int xcd = f & 7, s = f >> 3;            // s in [0,32)
    const int bm = xcd * 8 + (s >> 2);
    const int bn = s & 3;

    const int t = threadIdx.x;
    const int wave = t >> 6, lane = t & 63, quad = lane >> 4, lm = lane & 15;
    const int wm = wave >> 1, wn = wave & 1;

    const u16* asrc[2];
    const u16* bsrc[2];
    u16* adst[2];
    u16* bdst[2];
#pragma unroll
    for (int j = 0; j < 2; j++) {
        const int r = j * 64 + wave * 16 + (lane >> 2);
        const int cg = ((lane & 3) ^ (r & 3)) * 8;
        asrc[j] = &X [(size_t)(bm * 128 + r) * 512 + cg];
        bsrc[j] = &Wt[(size_t)(bn * 128 + r) * 512 + cg];
        adst[j] = &lds_a[(j * 2048) + wave * 512];
        bdst[j] = &lds_b[(j * 2048) + wave * 512];
    }

    f32x4 acc[4][4];
    const f32x4 zz = {0.f, 0.f, 0.f, 0.f};
#pragma unroll
    for (int i = 0; i < 4; i++)
#pragma unroll
        for (int j = 0; j < 4; j++) acc[i][j] = zz;

    for (int k0 = 0; k0 < 512; k0 += 32) {
        gload_lds16(asrc[0] + k0, adst[0]);
        gload_lds16(asrc[1] + k0, adst[1]);
        gload_lds16(bsrc[0] + k0, bdst[0]);
        gload_lds16(bsrc[1] + k0, bdst[1]);
        __syncthreads();
        bf16x8 af[4], bfr[4];
        const int cxor = (quad ^ (lm & 3)) * 8;
#pragma unroll
        for (int mi = 0; mi < 4; mi++)
            af[mi] = *(const bf16x8*)&lds_a[(wm * 64 + mi * 16 + lm) * 32 + cxor];
#pragma unroll
        for (int ni = 0; ni < 4; ni++)
            bfr[ni] = *(const bf16x8*)&lds_b[(wn * 64 + ni * 16 + lm) * 32 + cxor];
#pragma unroll
        for (int mi = 0; mi < 4; mi++)
#pragma unroll
            for (int ni = 0; ni < 4; ni++)
                acc[mi][ni] = MFMA16(af[mi], bfr[ni], acc[mi][ni], 0, 0, 0);
        __syncthreads();
    }

#pragma unroll
    for (int mi = 0; mi < 4; mi++) {
#pragma unroll
        for (int ni = 0; ni < 4; ni++) {
            const int col = bn * 128 + wn * 64 + ni * 16 + lm;
            const float bv_ = bo[col];
#pragma unroll
            for (int r = 0; r < 4; r++) {
                const int row = bm * 128 + wm * 64 + mi * 16 + quad * 4 + r;
                const size_t off = (size_t)row * 512 + col;
                outf[off] = resid[off] + fmaxf(acc[mi][ni][r] + bv_, 0.f);
            }
        }
    }
}

// ---------------------------------------------------------------------------
// Attention (R13-verified, best 44.6us): block = (b, h, 64 q-rows), 4 waves
// x 16 q, grid 1024, 16 waves/CU. K AND V staged in LDS via reg double-
// buffer (coalesced VMEM); 2 barriers/tile. Mask bias via 4 coalesced VMEM
// loads/tile. P: R8-verified per-wave RNE-bf16-through-LDS. XCD swizzle.
// ---------------------------------------------------------------------------
__global__ __launch_bounds__(256, 4) void attn_kernel(
    const u16* __restrict__ qb, const u16* __restrict__ kb, const u16* __restrict__ vtg,
    const int* __restrict__ mask, float* __restrict__ O)
{
    __shared__ __align__(16) u16 k_tile[64 * 88];       // [key][d]
    __shared__ __align__(16) u16 vt[64 * 88];           // [d][key]
    __shared__ __align__(16) u16 p_st[4 * 16 * 88];     // per-wave [qrow][key]

    // XCD swizzle: xcd = i&7; all 16 q-tiles of one (b,h) land on one XCD.
    const int i = blockIdx.x;
    const int s_ = i >> 3;
    const int bh = (i & 7) + 8 * (s_ >> 4);
    const int qt = s_ & 15;
    const int b = bh >> 3, h = bh & 7;

    const int t = threadIdx.x, wave = t >> 6, lane = t & 63;
    const int quad = lane >> 4, lm = lane & 15;
    const int qbase = qt * 64 + wave * 16;
    const size_t baseb = (size_t)b * 1024 * 512;
    const size_t vbase = (size_t)((b * 8 + h) * 64) * 1024;
    const int* mrow = &mask[b * 1024];

    // Q A-frags: 1 m-tile (16 q-rows) x 2 d-halves
    bf16x8 aq[2];
#pragma unroll
    for (int ks = 0; ks < 2; ks++)
        aq[ks] = *(const bf16x8*)&qb[baseb +
            (size_t)(qbase + lm) * 512 + h * 64 + ks * 32 + quad * 8];

    float lsum[4] = {0.f, 0.f, 0.f, 0.f};
    f32x4 oacc[4];
    const f32x4 zz = {0.f, 0.f, 0.f, 0.f};
#pragma unroll
    for (int c = 0; c < 4; c++) oacc[c] = zz;

    const float SC2 = 0.125f * 1.44269504088896341f; // (1/sqrt(64)) * log2(e)
    const int srow = t >> 2, scol = (t & 3) * 16;    // staging: 64 rows x 64
    u16* pw = &p_st[wave * 16 * 88];

    const u16* kgp = &kb[baseb + (size_t)srow * 512 + h * 64 + scol];
    const u16* vgp = &vtg[vbase + (size_t)srow * 1024 + scol];

    bf16x8 kA0, kA1, vA0, vA1, kB0, kB1, vB0, vB1;

    auto load_t = [&](int kt, bf16x8& k0, bf16x8& k1, bf16x8& v0, bf16x8& v1) {
        const u16* kp = kgp + (size_t)kt * 64 * 512;
        k0 = *(const bf16x8*)kp;
        k1 = *(const bf16x8*)(kp + 8);
        const u16* vp = vgp + kt * 64;
        v0 = *(const bf16x8*)vp;
        v1 = *(const bf16x8*)(vp + 8);
    };
    auto store_t = [&](bf16x8 k0, bf16x8 k1, bf16x8 v0, bf16x8 v1) {
        *(bf16x8*)&k_tile[srow * 88 + scol]     = k0;
        *(bf16x8*)&k_tile[srow * 88 + scol + 8] = k1;
        *(bf16x8*)&vt[srow * 88 + scol]     = v0;
        *(bf16x8*)&vt[srow * 88 + scol + 8] = v1;
    };

    auto compute_t = [&](int kt) {
        const int keyg = kt * 64;
        // mask bias per n-tile via coalesced VMEM (0 / -30000, same values)
        float bias_n[4];
#pragma unroll
        for (int n = 0; n < 4; n++)
            bias_n[n] = mrow[keyg + n * 16 + lm] ? 0.0f : -30000.0f;

        bf16x8 bk[4][2];
#pragma unroll
        for (int n = 0; n < 4; n++)
#pragma unroll
            for (int ks = 0; ks < 2; ks++)
                bk[n][ks] = *(const bf16x8*)&k_tile[(n * 16 + lm) * 88 + ks * 32 + quad * 8];

#pragma unroll
        for (int n = 0; n < 4; n++) {
            f32x4 S = zz;
            __builtin_amdgcn_s_setprio(1);
            S = MFMA16(aq[0], bk[n][0], S, 0, 0, 0);
            S = MFMA16(aq[1], bk[n][1], S, 0, 0, 0);
            __builtin_amdgcn_s_setprio(0);
#pragma unroll
            for (int r = 0; r < 4; r++) {
                float p = __builtin_amdgcn_exp2f(__builtin_fmaf(S[r], SC2, bias_n[n]));
                lsum[r] += p;
                pw[(quad * 4 + r) * 88 + n * 16 + lm] = f2bf(p);
            }
        }
        // no barrier: pw is per-wave; in-wave LDS RAW is program-ordered.

#pragma unroll
        for (int ks = 0; ks < 2; ks++) {
            bf16x8 ap = *(const bf16x8*)&pw[lm * 88 + ks * 32 + quad * 8];
            __builtin_amdgcn_s_setprio(1);
#pragma unroll
            for (int c = 0; c < 4; c++) {
                bf16x8 bv_ = *(const bf16x8*)&vt[(c * 16 + lm) * 88 + ks * 32 + quad * 8];
                oacc[c] = MFMA16(ap, bv_, oacc[c], 0, 0, 0);
            }
            __builtin_amdgcn_s_setprio(0);
        }
    };

    // prologue: tile 0 into regs
    load_t(0, kA0, kA1, vA0, vA1);

    for (int kt = 0; kt < 16; kt += 2) {
        store_t(kA0, kA1, vA0, vA1);          // vmcnt wait for tile kt here
        load_t(kt + 1, kB0, kB1, vB0, vB1);   // issue tile kt+1 (hidden)
        __syncthreads();
        compute_t(kt);
        __syncthreads();
        store_t(kB0, kB1, vB0, vB1);
        load_t((kt + 2) & 15, kA0, kA1, vA0, vA1); // &15: last iter dead-loads tile 0
        __syncthreads();
        compute_t(kt + 1);
        __syncthreads();
    }

    // reduce lsum across the 16 key-columns (lanes lm within each quad)
#pragma unroll
    for (int r = 0; r < 4; r++) {
        float s = lsum[r];
        s += __shfl_xor(s, 1); s += __shfl_xor(s, 2);
        s += __shfl_xor(s, 4); s += __shfl_xor(s, 8);
        lsum[r] = s;
    }

    // epilogue: O = q + P.V / l  (fp32, coalesced over lm)
#pragma unroll
    for (int c = 0; c < 4; c++)
#pragma unroll
        for (int r = 0; r < 4; r++) {
            const int row = qbase + quad * 4 + r;
            const int d = h * 64 + c * 16 + lm;
            const size_t off = baseb + (size_t)row * 512 + d;
            O[off] = bf2f(qb[off]) + oacc[c][r] / lsum[r];
        }
}

// ---------------------------------------------------------------------------
// Row LayerNorm over 512 (verified R5): fp32 in; optional bf16 + fp32 outs.
// ---------------------------------------------------------------------------
__global__ __launch_bounds__(256) void ln_kernel(
    const float* __restrict__ in, const float* __restrict__ g, const float* __restrict__ bsh,
    u16* __restrict__ outb, float* __restrict__ outf)
{
    const int row = blockIdx.x * 4 + (threadIdx.x >> 6);
    const int lane = threadIdx.x & 63;
    const float* x = in + (size_t)row * 512 + lane * 8;
    float v[8];
    *(f32x4*)&v[0] = *(const f32x4*)&x[0];
    *(f32x4*)&v[4] = *(const f32x4*)&x[4];
    float s = 0.f, sq = 0.f;
#pragma unroll
    for (int j = 0; j < 8; j++) { s += v[j]; sq += v[j] * v[j]; }
#pragma unroll
    for (int off = 1; off < 64; off <<= 1) {
        s += __shfl_xor(s, off);
        sq += __shfl_xor(sq, off);
    }
    const float mu = s * (1.f / 512.f);
    const float var = sq * (1.f / 512.f) - mu * mu;
    const float rs = rsqrtf(var + 1e-5f);
    float y[8];
#pragma unroll
    for (int j = 0; j < 8; j++) {
        int col = lane * 8 + j;
        y[j] = (v[j] - mu) * rs * g[col] + bsh[col];
    }
    if (outb != nullptr) {
        bf16x8 ov;
#pragma unroll
        for (int j = 0; j < 8; j++) ov[j] = (short)f2bf(y[j]);
        *(bf16x8*)&outb[(size_t)row * 512 + lane * 8] = ov;
    }
    if (outf != nullptr) {
        float* o = outf + (size_t)row * 512 + lane * 8;
        *(f32x4*)&o[0] = *(const f32x4*)&y[0];
        *(f32x4*)&o[4] = *(const f32x4*)&y[4];
    }
}

extern "C" void kernel_launch(void* const* d_in, const int* in_sizes, int n_in,
                              void* d_out, int out_size, void* d_ws, size_t ws_size,
                              hipStream_t stream) {
    const float* Q  = (const float*)d_in[0];
    const float* K  = (const float*)d_in[1];
    const int* mask = (const int*)d_in[2];
    const float* Wq = (const float*)d_in[3];
    const float* bq = (const float*)d_in[4];
    const float* Wk = (const float*)d_in[5];
    const float* bk = (const float*)d_in[6];
    const float* Wv = (const float*)d_in[7];
    const float* bv = (const float*)d_in[8];
    const float* Wo = (const float*)d_in[9];
    const float* bo = (const float*)d_in[10];
    const float* g0 = (const float*)d_in[11];
    const float* b0 = (const float*)d_in[12];
    const float* g1 = (const float*)d_in[13];
    const float* b1 = (const float*)d_in[14];
    float* out = (float*)d_out;

    char* ws = (char*)d_ws;
    const size_t MB = 1048576;
    u16*   wt  = (u16*)(ws);
    u16*   qb  = (u16*)(ws + 2 * MB);
    u16*   kb  = (u16*)(ws + 10 * MB);
    u16*   vtg = (u16*)(ws + 18 * MB);
    u16*   vb  = (u16*)(ws + 26 * MB);
    float* Of  = (float*)(ws + 26 * MB);  // overwrites vb (dead after transpose_v)
    u16*   O1b = (u16*)(ws + 2 * MB);     // reuse qb
    float* O1f = (float*)(ws + 10 * MB);  // reuse kb+vtg
    float* Uf  = (float*)(ws + 26 * MB);  // reuse Of

    transpose_w<<<dim3(16, 16, 4), 256, 0, stream>>>(Wq, Wk, Wv, Wo, wt);
    gemm_proj<<<dim3(4, 64, 3), 256, 0, stream>>>(Q, K, wt, bq, bk, bv, qb, kb, vb);
    transpose_v<<<dim3(32, 2, 64), 256, 0, stream>>>(vb, vtg);
    attn_kernel<<<1024, 256, 0, stream>>>(qb, kb, vtg, mask, Of);
    ln_kernel<<<2048, 256, 0, stream>>>(Of, g0, b0, O1b, O1f);
    gemm_mlp<<<dim3(4, 64, 1), 256, 0, stream>>>(O1b, wt, bo, O1f, Uf);
    ln_kernel<<<2048, 256, 0, stream>>>(Uf, g1, b1, nullptr, out);
}